// Round 5
// baseline (309.612 us; speedup 1.0000x reference)
//
#include <hip/hip_runtime.h>

#define T_DIM 2048
#define B_DIM 4
#define S_DIM 2048
#define E_DIM 1024
#define H_NUM 16
#define HD    64
#define NH    64      // B*H
#define SP1   2049    // S+1 (bias token appended)
#define SPAD  2112    // 33*64, padded key length
#define NCHUNK 33

typedef short bf16x8 __attribute__((ext_vector_type(8)));
typedef float f32x4  __attribute__((ext_vector_type(4)));
typedef float f32x16 __attribute__((ext_vector_type(16)));
typedef unsigned int u32;

// log2(e): softmax done in exp2 domain; folded into Q projection scale.
#define QSCALE 0.18033688011112042f   // 0.125 * log2(e)

#if __has_builtin(__builtin_amdgcn_exp2f)
__device__ __forceinline__ float exp2_fast(float x) { return __builtin_amdgcn_exp2f(x); }
#else
__device__ __forceinline__ float exp2_fast(float x) { return __expf(x * 0.6931471805599453f); }
#endif

__device__ __forceinline__ unsigned short f2bf(float x) {
    union { float f; unsigned int u; } v; v.f = x;
    unsigned int r = v.u + 0x7FFFu + ((v.u >> 16) & 1u);   // RNE
    return (unsigned short)(r >> 16);
}

__device__ __forceinline__ u32 cvtpk_bf16(float lo, float hi) {
    u32 r;
    asm("v_cvt_pk_bf16_f32 %0, %1, %2" : "=v"(r) : "v"(lo), "v"(hi));
    return r;
}
__device__ __forceinline__ void plswap(u32& a, u32& b) {
    asm("v_permlane32_swap_b32 %0, %1" : "+v"(a), "+v"(b));
}

// ---------------------------------------------------------------------------
// f32 -> bf16 bulk convert (weights only)
// ---------------------------------------------------------------------------
__global__ __launch_bounds__(256)
void cvt_bf16_k(const float* __restrict__ src, short* __restrict__ dst, int n8)
{
    int i = blockIdx.x * 256 + threadIdx.x;
    if (i >= n8) return;
    const float4* s = reinterpret_cast<const float4*>(src) + (size_t)i * 2;
    float4 a = s[0], b = s[1];
    bf16x8 o;
    o[0] = (short)f2bf(a.x); o[1] = (short)f2bf(a.y);
    o[2] = (short)f2bf(a.z); o[3] = (short)f2bf(a.w);
    o[4] = (short)f2bf(b.x); o[5] = (short)f2bf(b.y);
    o[6] = (short)f2bf(b.z); o[7] = (short)f2bf(b.w);
    *(reinterpret_cast<bf16x8*>(dst) + i) = o;
}

// ---------------------------------------------------------------------------
// bf16 MFMA GEMM with T14 register-prefetch staging (loads overlap compute).
// MODE 0..2: A is f32 (converted inline at LDS-write time).
// MODE 3: A is bf16, gathered from head-major o_h.
// ---------------------------------------------------------------------------
template<int MODE>
__global__ __launch_bounds__(256)
void gemm_bf16(const void* __restrict__ Ap, const short* __restrict__ W,
               const float* __restrict__ bias, void* __restrict__ outp)
{
    __shared__ short As[128][72];
    __shared__ short Bs[128][72];
    const int bm = blockIdx.x, bn = blockIdx.y;
    const int tid = threadIdx.x;
    const int l = tid & 63, w = tid >> 6;
    const int wr = w >> 1, wc = w & 1;
    const int lr = l & 15, lg = l >> 4;
    const int rb = tid >> 3, cg = tid & 7;   // staging coords

    float4 paA[4], paB[4];   // modes 0-2: 8 f32 of A per staging step
    bf16x8 pa3[4];           // mode 3: bf16 A
    bf16x8 pb[4];            // W

    auto load_tiles = [&](int k0) {
#pragma unroll
        for (int it = 0; it < 4; ++it) {
            const int row = it * 32 + rb;
            if (MODE == 3) {
                const int m = bm * 128 + row;
                const size_t asrc =
                    ((size_t)((m & 3) * 16 + (k0 >> 6)) * T_DIM + (m >> 2)) * HD + cg * 8;
                pa3[it] = *reinterpret_cast<const bf16x8*>((const short*)Ap + asrc);
            } else {
                const float* ap = (const float*)Ap + (size_t)(bm * 128 + row) * E_DIM + k0 + cg * 8;
                paA[it] = *reinterpret_cast<const float4*>(ap);
                paB[it] = *reinterpret_cast<const float4*>(ap + 4);
            }
            pb[it] = *reinterpret_cast<const bf16x8*>(
                W + (size_t)(bn * 128 + row) * E_DIM + k0 + cg * 8);
        }
    };
    auto write_tiles = [&]() {
#pragma unroll
        for (int it = 0; it < 4; ++it) {
            const int row = it * 32 + rb;
            if (MODE == 3) {
                *reinterpret_cast<bf16x8*>(&As[row][cg * 8]) = pa3[it];
            } else {
                uint4 st;
                st.x = cvtpk_bf16(paA[it].x, paA[it].y); st.y = cvtpk_bf16(paA[it].z, paA[it].w);
                st.z = cvtpk_bf16(paB[it].x, paB[it].y); st.w = cvtpk_bf16(paB[it].z, paB[it].w);
                *reinterpret_cast<uint4*>(&As[row][cg * 8]) = st;
            }
            *reinterpret_cast<bf16x8*>(&Bs[row][cg * 8]) = pb[it];
        }
    };

    load_tiles(0);
    write_tiles();
    __syncthreads();

    f32x4 acc[4][4] = {};

    for (int k0 = 0; k0 < E_DIM; k0 += 64) {
        const bool more = (k0 + 64 < E_DIM);
        if (more) load_tiles(k0 + 64);      // latency hidden under compute

        __builtin_amdgcn_s_setprio(1);
#pragma unroll
        for (int c = 0; c < 2; ++c) {
            bf16x8 af[4], bf[4];
#pragma unroll
            for (int mi = 0; mi < 4; ++mi)
                af[mi] = *reinterpret_cast<const bf16x8*>(&As[wr * 64 + mi * 16 + lr][c * 32 + lg * 8]);
#pragma unroll
            for (int ni = 0; ni < 4; ++ni)
                bf[ni] = *reinterpret_cast<const bf16x8*>(&Bs[wc * 64 + ni * 16 + lr][c * 32 + lg * 8]);
#pragma unroll
            for (int mi = 0; mi < 4; ++mi)
#pragma unroll
                for (int ni = 0; ni < 4; ++ni)
                    acc[mi][ni] = __builtin_amdgcn_mfma_f32_16x16x32_bf16(
                        af[mi], bf[ni], acc[mi][ni], 0, 0, 0);
        }
        __builtin_amdgcn_s_setprio(0);

        if (more) {
            __syncthreads();     // everyone done reading current tile
            write_tiles();
            __syncthreads();     // new tile visible
        }
    }

#pragma unroll
    for (int mi = 0; mi < 4; ++mi)
#pragma unroll
        for (int ni = 0; ni < 4; ++ni) {
            const int colg = bn * 128 + wc * 64 + ni * 16 + lr;
            const float bv = bias[colg];
#pragma unroll
            for (int r = 0; r < 4; ++r) {
                const int m = bm * 128 + wr * 64 + mi * 16 + lg * 4 + r;
                float v = acc[mi][ni][r] + bv;
                if (MODE == 3) {
                    ((float*)outp)[(size_t)m * E_DIM + colg] = v;
                } else {
                    if (MODE == 0) v *= QSCALE;
                    const int seq = m >> 2, b = m & 3;
                    const int head = colg >> 6, d = colg & 63;
                    const int sd = (MODE == 0) ? T_DIM : SPAD;
                    ((short*)outp)[((size_t)(b * 16 + head) * sd + seq) * HD + d] = (short)f2bf(v);
                }
            }
        }
}

// append bias_k/bias_v token at s=2048 (bf16), zero rows 2049..2111
__global__ void fill_kv_pad(short* __restrict__ k_h, short* __restrict__ v_h,
                            const float* __restrict__ bias_k,
                            const float* __restrict__ bias_v)
{
    const int d   = threadIdx.x;
    const int row = S_DIM + blockIdx.x;
    const int n   = blockIdx.y;
    short bk = 0, bv = 0;
    if (row == S_DIM) {
        bk = (short)f2bf(bias_k[(n & 15) * HD + d]);
        bv = (short)f2bf(bias_v[(n & 15) * HD + d]);
    }
    const size_t idx = ((size_t)n * SPAD + row) * HD + d;
    k_h[idx] = bk;
    v_h[idx] = bv;
}

// ---------------------------------------------------------------------------
// Swapped 32x32 MFMA flash attention; reg-prefetch dbuf (T14) +
// XCD-aware block swizzle (T1): all 16 q-tiles of one n on one XCD, so
// K/V re-reads are L2 hits.
// ---------------------------------------------------------------------------
__global__ __launch_bounds__(256)
void attn_mfma(const short* __restrict__ q_h, const short* __restrict__ k_h,
               const short* __restrict__ v_h, short* __restrict__ o_h,
               float* __restrict__ m_arr, float* __restrict__ l_arr)
{
    __shared__ short KsD[2][64 * 64];
    __shared__ short VtD[2][64 * 64];

    // XCD swizzle: 1024 blocks, 8 XCDs; xcd gets n in [8*xcd, 8*xcd+8)
    const int id = blockIdx.x;
    const int xcd = id & 7, slot = id >> 3;        // slot 0..127
    const int n = xcd * 8 + (slot >> 4);
    const int q0 = (slot & 15) * 128;

    const int tid = threadIdx.x, l = tid & 63, w = tid >> 6;
    const int ql = l & 31;
    const int hi = l >> 5;
    const int qrow = q0 + w * 32 + ql;

    const int krow = tid >> 3, kcg = tid & 7;
    const int kswz = (kcg * 16) ^ ((krow & 7) << 4);
    const int sp = tid & 31, d0 = (tid >> 5) * 8;

    const short* kbase = k_h + (size_t)n * SPAD * HD;
    const short* vbase = v_h + (size_t)n * SPAD * HD;

    bf16x8 aq0, aq1, aq2, aq3;
    {
        const short* qp = q_h + ((size_t)n * T_DIM + qrow) * HD + hi * 8;
        aq0 = *(const bf16x8*)(qp);
        aq1 = *(const bf16x8*)(qp + 16);
        aq2 = *(const bf16x8*)(qp + 32);
        aq3 = *(const bf16x8*)(qp + 48);
    }

    // prologue: chunk 0 -> regs -> LDS buf 0
    bf16x8 pk0 = *(const bf16x8*)(kbase + (size_t)krow * HD + kcg * 8);
    bf16x8 pk1 = *(const bf16x8*)(kbase + (size_t)(32 + krow) * HD + kcg * 8);
    bf16x8 pv0 = *(const bf16x8*)(vbase + (size_t)(2 * sp) * HD + d0);
    bf16x8 pv1 = *(const bf16x8*)(vbase + (size_t)(2 * sp + 1) * HD + d0);
    {
        char* KsB = (char*)KsD[0];
        char* VtB = (char*)VtD[0];
        *(bf16x8*)(KsB + krow * 128 + kswz) = pk0;
        *(bf16x8*)(KsB + (32 + krow) * 128 + kswz) = pk1;
#pragma unroll
        for (int j = 0; j < 8; ++j) {
            u32 pk = (u32)(unsigned short)pv0[j] | ((u32)(unsigned short)pv1[j] << 16);
            const int d = d0 + j;
            *(u32*)(VtB + d * 128 + ((4 * sp) ^ ((d & 7) << 4))) = pk;
        }
    }
    __syncthreads();

    float m_run = -1e30f, l_run = 0.f;
    f32x16 accA, accB;
#pragma unroll
    for (int r = 0; r < 16; ++r) { accA[r] = 0.f; accB[r] = 0.f; }

    for (int kc = 0; kc < NCHUNK; ++kc) {
        const char* KsB = (const char*)KsD[kc & 1];
        const char* VtB = (const char*)VtD[kc & 1];
        const bool more = (kc + 1 < NCHUNK);

        if (more) {
            const int s0n = (kc + 1) * 64;
            pk0 = *(const bf16x8*)(kbase + (size_t)(s0n + krow) * HD + kcg * 8);
            pk1 = *(const bf16x8*)(kbase + (size_t)(s0n + 32 + krow) * HD + kcg * 8);
            pv0 = *(const bf16x8*)(vbase + (size_t)(s0n + 2 * sp) * HD + d0);
            pv1 = *(const bf16x8*)(vbase + (size_t)(s0n + 2 * sp + 1) * HD + d0);
        }

        // ---- QK^T ----
        f32x16 sc0, sc1;
#pragma unroll
        for (int r = 0; r < 16; ++r) { sc0[r] = 0.f; sc1[r] = 0.f; }
        __builtin_amdgcn_s_setprio(1);
#pragma unroll
        for (int sl = 0; sl < 4; ++sl) {
            const int cb = ((sl * 32) + hi * 16) ^ ((ql & 7) << 4);
            bf16x8 kf0 = *(const bf16x8*)(KsB + ql * 128 + cb);
            bf16x8 kf1 = *(const bf16x8*)(KsB + (32 + ql) * 128 + cb);
            bf16x8 qf = (sl == 0) ? aq0 : (sl == 1) ? aq1 : (sl == 2) ? aq2 : aq3;
            sc0 = __builtin_amdgcn_mfma_f32_32x32x16_bf16(kf0, qf, sc0, 0, 0, 0);
            sc1 = __builtin_amdgcn_mfma_f32_32x32x16_bf16(kf1, qf, sc1, 0, 0, 0);
        }
        __builtin_amdgcn_s_setprio(0);

        const int s0 = kc * 64;
        if (s0 + 64 > SP1) {
#pragma unroll
            for (int r = 0; r < 16; ++r) {
                const int key = (r & 3) + 8 * (r >> 2) + 4 * hi;
                if (s0 + key >= SP1)      sc0[r] = -1e30f;
                if (s0 + 32 + key >= SP1) sc1[r] = -1e30f;
            }
        }

        // ---- online softmax (exp2 domain), defer-max THR=8 ----
        float mx = sc0[0];
#pragma unroll
        for (int r = 1; r < 16; ++r) mx = fmaxf(mx, sc0[r]);
#pragma unroll
        for (int r = 0; r < 16; ++r) mx = fmaxf(mx, sc1[r]);
        mx = fmaxf(mx, __shfl_xor(mx, 32));
        if (!__all(mx - m_run <= 8.0f)) {
            const float mnew = fmaxf(m_run, mx);
            const float fac = exp2_fast(m_run - mnew);
            l_run *= fac;
#pragma unroll
            for (int r = 0; r < 16; ++r) { accA[r] *= fac; accB[r] *= fac; }
            m_run = mnew;
        }
        float ps = 0.f;
        float p0[16], p1[16];
#pragma unroll
        for (int r = 0; r < 16; ++r) { p0[r] = exp2_fast(sc0[r] - m_run); ps += p0[r]; }
#pragma unroll
        for (int r = 0; r < 16; ++r) { p1[r] = exp2_fast(sc1[r] - m_run); ps += p1[r]; }
        ps += __shfl_xor(ps, 32);
        l_run += ps;

        // ---- P fragments in-register (cvt_pk + permlane32_swap) ----
        union PF { u32 u[4]; bf16x8 v; };
        PF pf0, pf1, pf2, pf3;
        {
            u32 a0 = cvtpk_bf16(p0[0], p0[1]),   b0 = cvtpk_bf16(p0[4], p0[5]);   plswap(a0, b0);
            u32 a1 = cvtpk_bf16(p0[2], p0[3]),   b1 = cvtpk_bf16(p0[6], p0[7]);   plswap(a1, b1);
            u32 a2 = cvtpk_bf16(p0[8], p0[9]),   b2 = cvtpk_bf16(p0[12], p0[13]); plswap(a2, b2);
            u32 a3 = cvtpk_bf16(p0[10], p0[11]), b3 = cvtpk_bf16(p0[14], p0[15]); plswap(a3, b3);
            pf0.u[0] = a0; pf0.u[1] = a1; pf0.u[2] = b0; pf0.u[3] = b1;
            pf1.u[0] = a2; pf1.u[1] = a3; pf1.u[2] = b2; pf1.u[3] = b3;
            u32 c0 = cvtpk_bf16(p1[0], p1[1]),   d0_ = cvtpk_bf16(p1[4], p1[5]);   plswap(c0, d0_);
            u32 c1 = cvtpk_bf16(p1[2], p1[3]),   d1_ = cvtpk_bf16(p1[6], p1[7]);   plswap(c1, d1_);
            u32 c2 = cvtpk_bf16(p1[8], p1[9]),   d2_ = cvtpk_bf16(p1[12], p1[13]); plswap(c2, d2_);
            u32 c3 = cvtpk_bf16(p1[10], p1[11]), d3_ = cvtpk_bf16(p1[14], p1[15]); plswap(c3, d3_);
            pf2.u[0] = c0; pf2.u[1] = c1; pf2.u[2] = d0_; pf2.u[3] = d1_;
            pf3.u[0] = c2; pf3.u[1] = c3; pf3.u[2] = d2_; pf3.u[3] = d3_;
        }

        // ---- PV ----
        __builtin_amdgcn_s_setprio(1);
#pragma unroll
        for (int ksl = 0; ksl < 4; ++ksl) {
            const int cb = ((ksl * 32) + hi * 16) ^ ((ql & 7) << 4);
            bf16x8 vf0 = *(const bf16x8*)(VtB + ql * 128 + cb);
            bf16x8 vf1 = *(const bf16x8*)(VtB + (32 + ql) * 128 + cb);
            const bf16x8 pv = (ksl == 0) ? pf0.v : (ksl == 1) ? pf1.v : (ksl == 2) ? pf2.v : pf3.v;
            accA = __builtin_amdgcn_mfma_f32_32x32x16_bf16(vf0, pv, accA, 0, 0, 0);
            accB = __builtin_amdgcn_mfma_f32_32x32x16_bf16(vf1, pv, accB, 0, 0, 0);
        }
        __builtin_amdgcn_s_setprio(0);

        if (more) {
            char* KsN = (char*)KsD[(kc & 1) ^ 1];
            char* VtN = (char*)VtD[(kc & 1) ^ 1];
            *(bf16x8*)(KsN + krow * 128 + kswz) = pk0;
            *(bf16x8*)(KsN + (32 + krow) * 128 + kswz) = pk1;
#pragma unroll
            for (int j = 0; j < 8; ++j) {
                u32 pk = (u32)(unsigned short)pv0[j] | ((u32)(unsigned short)pv1[j] << 16);
                const int d = d0 + j;
                *(u32*)(VtN + d * 128 + ((4 * sp) ^ ((d & 7) << 4))) = pk;
            }
            __syncthreads();
        }
    }

    const float il = 1.0f / l_run;
    short* orow = o_h + ((size_t)n * T_DIM + qrow) * HD;
#pragma unroll
    for (int rq = 0; rq < 4; ++rq) {
        uint2 st;
        st.x = cvtpk_bf16(accA[rq * 4 + 0] * il, accA[rq * 4 + 1] * il);
        st.y = cvtpk_bf16(accA[rq * 4 + 2] * il, accA[rq * 4 + 3] * il);
        *(uint2*)(orow + rq * 8 + hi * 4) = st;
        uint2 st2;
        st2.x = cvtpk_bf16(accB[rq * 4 + 0] * il, accB[rq * 4 + 1] * il);
        st2.y = cvtpk_bf16(accB[rq * 4 + 2] * il, accB[rq * 4 + 3] * il);
        *(uint2*)(orow + 32 + rq * 8 + hi * 4) = st2;
    }
    if (hi == 0) {
        m_arr[n * T_DIM + qrow] = m_run;
        l_arr[n * T_DIM + qrow] = l_run;
    }
}

// ---------------------------------------------------------------------------
// avg_weights: reg-prefetch dbuf + XCD swizzle (33 key-tiles of one n share
// its Q stream via L2).
// ---------------------------------------------------------------------------
__global__ __launch_bounds__(256)
void colsum_mfma(const short* __restrict__ q_h, const short* __restrict__ k_h,
                 const float* __restrict__ m_arr, const float* __restrict__ l_arr,
                 float* __restrict__ avg_out)
{
    __shared__ short Qs[2][64][72];
    __shared__ float msh[2][64];
    __shared__ float lih[2][64];

    // XCD swizzle: 2112 = 8 * 264 blocks; xcd gets n in [8*xcd, 8*xcd+8)
    const int id = blockIdx.x;
    const int xcd = id & 7, slot = id >> 3;        // slot 0..263
    const int n = xcd * 8 + slot / 33;
    const int s0 = (slot % 33) * 64;

    const int tid = threadIdx.x, l = tid & 63, w = tid >> 6;
    const int lr = l & 15, lg = l >> 4;
    const int qr = tid >> 3, qcg = tid & 7;

    const short* qbase = q_h + (size_t)n * T_DIM * HD;

    bf16x8 ak[2];
#pragma unroll
    for (int c = 0; c < 2; ++c)
        ak[c] = *reinterpret_cast<const bf16x8*>(
            k_h + ((size_t)n * SPAD + s0 + w * 16 + lr) * HD + c * 32 + lg * 8);

    bf16x8 qa = *(const bf16x8*)(qbase + (size_t)qr * HD + qcg * 8);
    bf16x8 qb = *(const bf16x8*)(qbase + (size_t)(32 + qr) * HD + qcg * 8);
    float mlv = 0.f;
    if (tid < 64) mlv = m_arr[n * T_DIM + tid];
    else if (tid < 128) mlv = l_arr[n * T_DIM + tid - 64];
    *(bf16x8*)&Qs[0][qr][qcg * 8] = qa;
    *(bf16x8*)&Qs[0][32 + qr][qcg * 8] = qb;
    if (tid < 64) msh[0][tid] = mlv;
    else if (tid < 128) lih[0][tid - 64] = 1.0f / mlv;
    __syncthreads();

    float csum[4] = {0.f, 0.f, 0.f, 0.f};

    for (int it = 0; it < T_DIM / 64; ++it) {
        const int buf = it & 1;
        const bool more = (it + 1 < T_DIM / 64);
        if (more) {
            const int qo = (it + 1) * 64;
            qa = *(const bf16x8*)(qbase + (size_t)(qo + qr) * HD + qcg * 8);
            qb = *(const bf16x8*)(qbase + (size_t)(qo + 32 + qr) * HD + qcg * 8);
            if (tid < 64) mlv = m_arr[n * T_DIM + qo + tid];
            else if (tid < 128) mlv = l_arr[n * T_DIM + qo + tid - 64];
        }
        __builtin_amdgcn_s_setprio(1);
#pragma unroll
        for (int qt = 0; qt < 4; ++qt) {
            bf16x8 bq0 = *reinterpret_cast<const bf16x8*>(&Qs[buf][qt * 16 + lr][lg * 8]);
            bf16x8 bq1 = *reinterpret_cast<const bf16x8*>(&Qs[buf][qt * 16 + lr][32 + lg * 8]);
            f32x4 z = {0.f, 0.f, 0.f, 0.f};
            z = __builtin_amdgcn_mfma_f32_16x16x32_bf16(ak[0], bq0, z, 0, 0, 0);
            z = __builtin_amdgcn_mfma_f32_16x16x32_bf16(ak[1], bq1, z, 0, 0, 0);
            const float mq = msh[buf][qt * 16 + lr];
            const float lq = lih[buf][qt * 16 + lr];
#pragma unroll
            for (int r = 0; r < 4; ++r)
                csum[r] += exp2_fast(z[r] - mq) * lq;
        }
        __builtin_amdgcn_s_setprio(0);
        if (more) {
            *(bf16x8*)&Qs[buf ^ 1][qr][qcg * 8] = qa;
            *(bf16x8*)&Qs[buf ^ 1][32 + qr][qcg * 8] = qb;
            if (tid < 64) msh[buf ^ 1][tid] = mlv;
            else if (tid < 128) lih[buf ^ 1][tid - 64] = 1.0f / mlv;
            __syncthreads();
        }
    }

#pragma unroll
    for (int r = 0; r < 4; ++r) {
        float v = csum[r];
        v += __shfl_xor(v, 1, 16);
        v += __shfl_xor(v, 2, 16);
        v += __shfl_xor(v, 4, 16);
        v += __shfl_xor(v, 8, 16);
        if (lr == 0) {
            const int key = s0 + w * 16 + lg * 4 + r;
            if (key < SP1) avg_out[(size_t)n * SP1 + key] = v * 0.0625f;
        }
    }
}

// ---------------------------------------------------------------------------
extern "C" void kernel_launch(void* const* d_in, const int* in_sizes, int n_in,
                              void* d_out, int out_size, void* d_ws, size_t ws_size,
                              hipStream_t stream)
{
    const float* query   = (const float*)d_in[0];
    const float* key     = (const float*)d_in[1];
    const float* value   = (const float*)d_in[2];
    const float* wq      = (const float*)d_in[3];
    const float* wk      = (const float*)d_in[4];
    const float* wv      = (const float*)d_in[5];
    const float* in_bias = (const float*)d_in[6];
    const float* bias_k  = (const float*)d_in[7];
    const float* bias_v  = (const float*)d_in[8];
    const float* wo      = (const float*)d_in[9];
    const float* out_b   = (const float*)d_in[10];
    float* out = (float*)d_out;

    short* wqb = (short*)d_ws;                           // [1024][1024] bf16 x4
    short* wkb = wqb + (size_t)E_DIM * E_DIM;
    short* wvb = wkb + (size_t)E_DIM * E_DIM;
    short* wob = wvb + (size_t)E_DIM * E_DIM;
    short* q_h = wob + (size_t)E_DIM * E_DIM;            // [64][2048][64]
    short* k_h = q_h + (size_t)NH * T_DIM * HD;          // [64][2112][64]
    short* v_h = k_h + (size_t)NH * SPAD * HD;           // [64][2112][64]
    short* o_h = v_h + (size_t)NH * SPAD * HD;           // [64][2048][64]
    float* m_arr = (float*)(o_h + (size_t)NH * T_DIM * HD);
    float* l_arr = m_arr + (size_t)NH * T_DIM;

    const int n8_w = E_DIM * E_DIM / 8;
    const dim3 blk(256);
    hipLaunchKernelGGL(cvt_bf16_k, dim3((n8_w + 255) / 256), blk, 0, stream, wq, wqb, n8_w);
    hipLaunchKernelGGL(cvt_bf16_k, dim3((n8_w + 255) / 256), blk, 0, stream, wk, wkb, n8_w);
    hipLaunchKernelGGL(cvt_bf16_k, dim3((n8_w + 255) / 256), blk, 0, stream, wv, wvb, n8_w);
    hipLaunchKernelGGL(cvt_bf16_k, dim3((n8_w + 255) / 256), blk, 0, stream, wo, wob, n8_w);

    const dim3 gg(64, 8);
    hipLaunchKernelGGL((gemm_bf16<0>), gg, blk, 0, stream, (const void*)query, wqb, in_bias,             (void*)q_h);
    hipLaunchKernelGGL((gemm_bf16<1>), gg, blk, 0, stream, (const void*)key,   wkb, in_bias + E_DIM,     (void*)k_h);
    hipLaunchKernelGGL((gemm_bf16<2>), gg, blk, 0, stream, (const void*)value, wvb, in_bias + 2 * E_DIM, (void*)v_h);
    hipLaunchKernelGGL(fill_kv_pad, dim3(SPAD - S_DIM, NH), dim3(64), 0, stream,
                       k_h, v_h, bias_k, bias_v);
    hipLaunchKernelGGL(attn_mfma, dim3(1024), blk, 0, stream,
                       q_h, k_h, v_h, o_h, m_arr, l_arr);
    hipLaunchKernelGGL(colsum_mfma, dim3(2112), blk, 0, stream,
                       q_h, k_h, m_arr, l_arr, out + (size_t)T_DIM * B_DIM * E_DIM);
    hipLaunchKernelGGL((gemm_bf16<3>), gg, blk, 0, stream, (const void*)o_h, wob, out_b, (void*)out);
}

// Round 6
// 294.078 us; speedup vs baseline: 1.0528x; 1.0528x over previous
//
#include <hip/hip_runtime.h>

#define T_DIM 2048
#define B_DIM 4
#define S_DIM 2048
#define E_DIM 1024
#define H_NUM 16
#define HD    64
#define NH    64      // B*H
#define SP1   2049    // S+1 (bias token appended)
#define SPAD  2112    // 33*64, padded key length
#define NCHUNK 33

typedef short bf16x8 __attribute__((ext_vector_type(8)));
typedef short bf16x4 __attribute__((ext_vector_type(4)));
typedef float f32x4  __attribute__((ext_vector_type(4)));
typedef float f32x16 __attribute__((ext_vector_type(16)));
typedef unsigned int u32;

// log2(e): softmax done in exp2 domain; folded into Q projection scale.
#define QSCALE 0.18033688011112042f   // 0.125 * log2(e)

#if __has_builtin(__builtin_amdgcn_exp2f)
__device__ __forceinline__ float exp2_fast(float x) { return __builtin_amdgcn_exp2f(x); }
#else
__device__ __forceinline__ float exp2_fast(float x) { return __expf(x * 0.6931471805599453f); }
#endif

__device__ __forceinline__ unsigned short f2bf(float x) {
    union { float f; unsigned int u; } v; v.f = x;
    unsigned int r = v.u + 0x7FFFu + ((v.u >> 16) & 1u);   // RNE
    return (unsigned short)(r >> 16);
}

__device__ __forceinline__ u32 cvtpk_bf16(float lo, float hi) {
    u32 r;
    asm("v_cvt_pk_bf16_f32 %0, %1, %2" : "=v"(r) : "v"(lo), "v"(hi));
    return r;
}
__device__ __forceinline__ void plswap(u32& a, u32& b) {
    asm("v_permlane32_swap_b32 %0, %1" : "+v"(a), "+v"(b));
}

// ---------------------------------------------------------------------------
// All 4 weight matrices f32 -> bf16 in one launch. dst layout: wq|wk|wv|wo.
// ---------------------------------------------------------------------------
__global__ __launch_bounds__(256)
void cvt_w4(const float* __restrict__ w0, const float* __restrict__ w1,
            const float* __restrict__ w2, const float* __restrict__ w3,
            short* __restrict__ dst)
{
    const int y = blockIdx.y;
    const float* src = (y == 0) ? w0 : (y == 1) ? w1 : (y == 2) ? w2 : w3;
    short* d = dst + (size_t)y * E_DIM * E_DIM;
    const int i = blockIdx.x * 256 + threadIdx.x;     // 512 blocks * 256 = 131072 = E*E/8
    const float4* s = reinterpret_cast<const float4*>(src) + (size_t)i * 2;
    float4 a = s[0], b = s[1];
    uint4 o;
    o.x = cvtpk_bf16(a.x, a.y); o.y = cvtpk_bf16(a.z, a.w);
    o.z = cvtpk_bf16(b.x, b.y); o.w = cvtpk_bf16(b.z, b.w);
    *(reinterpret_cast<uint4*>(d) + i) = o;
}

// ---------------------------------------------------------------------------
// bf16 MFMA GEMM, 2-phase reg-prefetch staging.
// MODE 0: fused QKV projection — blockIdx.z in {0,1,2} picks input/weights/
//         bias/output; A is f32 (converted at LDS-write).
// MODE 3: out-proj — A bf16 gathered from head-major o_h; f32 output.
// ---------------------------------------------------------------------------
template<int MODE>
__global__ __launch_bounds__(256)
void gemm_bf16(const void* __restrict__ Xq, const void* __restrict__ Xk,
               const void* __restrict__ Xv, const short* __restrict__ Wall,
               const float* __restrict__ biasAll, void* __restrict__ outp)
{
    __shared__ short As[128][72];
    __shared__ short Bs[128][72];
    const int bm = blockIdx.x, bn = blockIdx.y;
    const int z = (MODE == 0) ? blockIdx.z : 0;
    const void* Ap = (MODE == 3) ? Xq : (z == 0) ? Xq : (z == 1) ? Xk : Xv;
    const short* W = Wall + (size_t)z * E_DIM * E_DIM;
    const float* bias = biasAll + z * E_DIM;

    const int tid = threadIdx.x;
    const int l = tid & 63, w = tid >> 6;
    const int wr = w >> 1, wc = w & 1;
    const int lr = l & 15, lg = l >> 4;
    const int rb = tid >> 3, cg = tid & 7;   // staging coords

    float4 paA[4], paB[4];
    bf16x8 pa3[4];
    bf16x8 pb[4];

    auto load_tiles = [&](int k0) {
#pragma unroll
        for (int it = 0; it < 4; ++it) {
            const int row = it * 32 + rb;
            if (MODE == 3) {
                const int m = bm * 128 + row;
                const size_t asrc =
                    ((size_t)((m & 3) * 16 + (k0 >> 6)) * T_DIM + (m >> 2)) * HD + cg * 8;
                pa3[it] = *reinterpret_cast<const bf16x8*>((const short*)Ap + asrc);
            } else {
                const float* ap = (const float*)Ap + (size_t)(bm * 128 + row) * E_DIM + k0 + cg * 8;
                paA[it] = *reinterpret_cast<const float4*>(ap);
                paB[it] = *reinterpret_cast<const float4*>(ap + 4);
            }
            pb[it] = *reinterpret_cast<const bf16x8*>(
                W + (size_t)(bn * 128 + row) * E_DIM + k0 + cg * 8);
        }
    };
    auto write_tiles = [&]() {
#pragma unroll
        for (int it = 0; it < 4; ++it) {
            const int row = it * 32 + rb;
            if (MODE == 3) {
                *reinterpret_cast<bf16x8*>(&As[row][cg * 8]) = pa3[it];
            } else {
                uint4 st;
                st.x = cvtpk_bf16(paA[it].x, paA[it].y); st.y = cvtpk_bf16(paA[it].z, paA[it].w);
                st.z = cvtpk_bf16(paB[it].x, paB[it].y); st.w = cvtpk_bf16(paB[it].z, paB[it].w);
                *reinterpret_cast<uint4*>(&As[row][cg * 8]) = st;
            }
            *reinterpret_cast<bf16x8*>(&Bs[row][cg * 8]) = pb[it];
        }
    };

    load_tiles(0);
    write_tiles();
    __syncthreads();

    f32x4 acc[4][4] = {};

    for (int k0 = 0; k0 < E_DIM; k0 += 64) {
        const bool more = (k0 + 64 < E_DIM);
        if (more) load_tiles(k0 + 64);

        __builtin_amdgcn_s_setprio(1);
#pragma unroll
        for (int c = 0; c < 2; ++c) {
            bf16x8 af[4], bf[4];
#pragma unroll
            for (int mi = 0; mi < 4; ++mi)
                af[mi] = *reinterpret_cast<const bf16x8*>(&As[wr * 64 + mi * 16 + lr][c * 32 + lg * 8]);
#pragma unroll
            for (int ni = 0; ni < 4; ++ni)
                bf[ni] = *reinterpret_cast<const bf16x8*>(&Bs[wc * 64 + ni * 16 + lr][c * 32 + lg * 8]);
#pragma unroll
            for (int mi = 0; mi < 4; ++mi)
#pragma unroll
                for (int ni = 0; ni < 4; ++ni)
                    acc[mi][ni] = __builtin_amdgcn_mfma_f32_16x16x32_bf16(
                        af[mi], bf[ni], acc[mi][ni], 0, 0, 0);
        }
        __builtin_amdgcn_s_setprio(0);

        if (more) {
            __syncthreads();
            write_tiles();
            __syncthreads();
        }
    }

#pragma unroll
    for (int mi = 0; mi < 4; ++mi)
#pragma unroll
        for (int ni = 0; ni < 4; ++ni) {
            const int colg = bn * 128 + wc * 64 + ni * 16 + lr;
            const float bv = bias[colg];
#pragma unroll
            for (int r = 0; r < 4; ++r) {
                const int m = bm * 128 + wr * 64 + mi * 16 + lg * 4 + r;
                float v = acc[mi][ni][r] + bv;
                if (MODE == 3) {
                    ((float*)outp)[(size_t)m * E_DIM + colg] = v;
                } else {
                    if (z == 0) v *= QSCALE;
                    const int seq = m >> 2, b = m & 3;
                    const int head = colg >> 6, d = colg & 63;
                    const int sd = (z == 0) ? T_DIM : SPAD;
                    short* ob = (short*)outp;
                    if (z == 1) ob += (size_t)NH * T_DIM * HD;
                    else if (z == 2) ob += (size_t)NH * T_DIM * HD + (size_t)NH * SPAD * HD;
                    ob[((size_t)(b * 16 + head) * sd + seq) * HD + d] = (short)f2bf(v);
                }
            }
        }
}

// append bias_k/bias_v token at s=2048 (bf16), zero rows 2049..2111
__global__ void fill_kv_pad(short* __restrict__ k_h, short* __restrict__ v_h,
                            const float* __restrict__ bias_k,
                            const float* __restrict__ bias_v)
{
    const int d   = threadIdx.x;
    const int row = S_DIM + blockIdx.x;
    const int n   = blockIdx.y;
    short bk = 0, bv = 0;
    if (row == S_DIM) {
        bk = (short)f2bf(bias_k[(n & 15) * HD + d]);
        bv = (short)f2bf(bias_v[(n & 15) * HD + d]);
    }
    const size_t idx = ((size_t)n * SPAD + row) * HD + d;
    k_h[idx] = bk;
    v_h[idx] = bv;
}

// ---------------------------------------------------------------------------
// Swapped 32x32 MFMA flash attention, 8-wave blocks (256 q), grid 512 =
// 2 blocks/CU = 4 waves/SIMD. Reg-prefetch dbuf, XCD swizzle, tree reductions.
// ---------------------------------------------------------------------------
__global__ __launch_bounds__(512, 4)
void attn_mfma(const short* __restrict__ q_h, const short* __restrict__ k_h,
               const short* __restrict__ v_h, short* __restrict__ o_h,
               float* __restrict__ m_arr, float* __restrict__ l_arr)
{
    __shared__ short KsD[2][64 * 64];
    __shared__ short VtD[2][64 * 64];

    // XCD swizzle: 512 blocks; xcd x gets n in [8x, 8x+8); 8 q-tiles per n.
    const int id = blockIdx.x;
    const int xcd = id & 7, slot = id >> 3;        // slot 0..63
    const int n = xcd * 8 + (slot >> 3);
    const int q0 = (slot & 7) * 256;

    const int tid = threadIdx.x, l = tid & 63, w = tid >> 6;   // w 0..7
    const int ql = l & 31;
    const int hi = l >> 5;
    const int qrow = q0 + w * 32 + ql;

    // staging coords (512 threads)
    const int krow = tid >> 3, kcg = tid & 7;            // K: 64 rows x 8 groups
    const int kswz = (kcg * 16) ^ ((krow & 7) << 4);
    const int sp = tid & 31, dq = tid >> 5;              // V: key-pair sp, d-quad dq (0..15)

    const short* kbase = k_h + (size_t)n * SPAD * HD;
    const short* vbase = v_h + (size_t)n * SPAD * HD;

    // Q fragments: B[col=q][k]; lane q = ql, k = sl*16 + hi*8 + j
    bf16x8 aq0, aq1, aq2, aq3;
    {
        const short* qp = q_h + ((size_t)n * T_DIM + qrow) * HD + hi * 8;
        aq0 = *(const bf16x8*)(qp);
        aq1 = *(const bf16x8*)(qp + 16);
        aq2 = *(const bf16x8*)(qp + 32);
        aq3 = *(const bf16x8*)(qp + 48);
    }

    // prologue: chunk 0 -> regs -> LDS buf 0
    bf16x8 pk  = *(const bf16x8*)(kbase + (size_t)krow * HD + kcg * 8);
    bf16x4 pva = *(const bf16x4*)(vbase + (size_t)(2 * sp) * HD + dq * 4);
    bf16x4 pvb = *(const bf16x4*)(vbase + (size_t)(2 * sp + 1) * HD + dq * 4);
    {
        char* KsB = (char*)KsD[0];
        char* VtB = (char*)VtD[0];
        *(bf16x8*)(KsB + krow * 128 + kswz) = pk;
#pragma unroll
        for (int j = 0; j < 4; ++j) {
            u32 pkd = (u32)(unsigned short)pva[j] | ((u32)(unsigned short)pvb[j] << 16);
            const int d = dq * 4 + j;
            *(u32*)(VtB + d * 128 + ((4 * sp) ^ ((d & 7) << 4))) = pkd;
        }
    }
    __syncthreads();

    float m_run = -1e30f, l_run = 0.f;
    f32x16 accA, accB;
#pragma unroll
    for (int r = 0; r < 16; ++r) { accA[r] = 0.f; accB[r] = 0.f; }

    for (int kc = 0; kc < NCHUNK; ++kc) {
        const char* KsB = (const char*)KsD[kc & 1];
        const char* VtB = (const char*)VtD[kc & 1];
        const bool more = (kc + 1 < NCHUNK);

        if (more) {
            const int s0n = (kc + 1) * 64;
            pk  = *(const bf16x8*)(kbase + (size_t)(s0n + krow) * HD + kcg * 8);
            pva = *(const bf16x4*)(vbase + (size_t)(s0n + 2 * sp) * HD + dq * 4);
            pvb = *(const bf16x4*)(vbase + (size_t)(s0n + 2 * sp + 1) * HD + dq * 4);
        }

        // ---- QK^T ----
        f32x16 sc0, sc1;
#pragma unroll
        for (int r = 0; r < 16; ++r) { sc0[r] = 0.f; sc1[r] = 0.f; }
        __builtin_amdgcn_s_setprio(1);
#pragma unroll
        for (int sl = 0; sl < 4; ++sl) {
            const int cb = ((sl * 32) + hi * 16) ^ ((ql & 7) << 4);
            bf16x8 kf0 = *(const bf16x8*)(KsB + ql * 128 + cb);
            bf16x8 kf1 = *(const bf16x8*)(KsB + (32 + ql) * 128 + cb);
            bf16x8 qf = (sl == 0) ? aq0 : (sl == 1) ? aq1 : (sl == 2) ? aq2 : aq3;
            sc0 = __builtin_amdgcn_mfma_f32_32x32x16_bf16(kf0, qf, sc0, 0, 0, 0);
            sc1 = __builtin_amdgcn_mfma_f32_32x32x16_bf16(kf1, qf, sc1, 0, 0, 0);
        }
        __builtin_amdgcn_s_setprio(0);

        const int s0 = kc * 64;
        if (s0 + 64 > SP1) {
#pragma unroll
            for (int r = 0; r < 16; ++r) {
                const int key = (r & 3) + 8 * (r >> 2) + 4 * hi;
                if (s0 + key >= SP1)      sc0[r] = -1e30f;
                if (s0 + 32 + key >= SP1) sc1[r] = -1e30f;
            }
        }

        // ---- online softmax (exp2 domain), tree reductions, defer-max ----
        float mv[16];
#pragma unroll
        for (int r = 0; r < 16; ++r) mv[r] = fmaxf(sc0[r], sc1[r]);
#pragma unroll
        for (int s = 8; s > 0; s >>= 1)
#pragma unroll
            for (int r = 0; r < s; ++r) mv[r] = fmaxf(mv[r], mv[r + s]);
        float mx = fmaxf(mv[0], __shfl_xor(mv[0], 32));
        if (!__all(mx - m_run <= 8.0f)) {
            const float mnew = fmaxf(m_run, mx);
            const float fac = exp2_fast(m_run - mnew);
            l_run *= fac;
#pragma unroll
            for (int r = 0; r < 16; ++r) { accA[r] *= fac; accB[r] *= fac; }
            m_run = mnew;
        }
        float p0[16], p1[16];
#pragma unroll
        for (int r = 0; r < 16; ++r) p0[r] = exp2_fast(sc0[r] - m_run);
#pragma unroll
        for (int r = 0; r < 16; ++r) p1[r] = exp2_fast(sc1[r] - m_run);
        float sv[16];
#pragma unroll
        for (int r = 0; r < 16; ++r) sv[r] = p0[r] + p1[r];
#pragma unroll
        for (int s = 8; s > 0; s >>= 1)
#pragma unroll
            for (int r = 0; r < s; ++r) sv[r] += sv[r + s];
        l_run += sv[0] + __shfl_xor(sv[0], 32);

        // ---- P fragments in-register (cvt_pk + permlane32_swap) ----
        union PF { u32 u[4]; bf16x8 v; };
        PF pf0, pf1, pf2, pf3;
        {
            u32 a0 = cvtpk_bf16(p0[0], p0[1]),   b0 = cvtpk_bf16(p0[4], p0[5]);   plswap(a0, b0);
            u32 a1 = cvtpk_bf16(p0[2], p0[3]),   b1 = cvtpk_bf16(p0[6], p0[7]);   plswap(a1, b1);
            u32 a2 = cvtpk_bf16(p0[8], p0[9]),   b2 = cvtpk_bf16(p0[12], p0[13]); plswap(a2, b2);
            u32 a3 = cvtpk_bf16(p0[10], p0[11]), b3 = cvtpk_bf16(p0[14], p0[15]); plswap(a3, b3);
            pf0.u[0] = a0; pf0.u[1] = a1; pf0.u[2] = b0; pf0.u[3] = b1;
            pf1.u[0] = a2; pf1.u[1] = a3; pf1.u[2] = b2; pf1.u[3] = b3;
            u32 c0 = cvtpk_bf16(p1[0], p1[1]),   d0_ = cvtpk_bf16(p1[4], p1[5]);   plswap(c0, d0_);
            u32 c1 = cvtpk_bf16(p1[2], p1[3]),   d1_ = cvtpk_bf16(p1[6], p1[7]);   plswap(c1, d1_);
            u32 c2 = cvtpk_bf16(p1[8], p1[9]),   d2_ = cvtpk_bf16(p1[12], p1[13]); plswap(c2, d2_);
            u32 c3 = cvtpk_bf16(p1[10], p1[11]), d3_ = cvtpk_bf16(p1[14], p1[15]); plswap(c3, d3_);
            pf2.u[0] = c0; pf2.u[1] = c1; pf2.u[2] = d0_; pf2.u[3] = d1_;
            pf3.u[0] = c2; pf3.u[1] = c3; pf3.u[2] = d2_; pf3.u[3] = d3_;
        }

        // ---- PV: O^T += Vt @ P ----
        __builtin_amdgcn_s_setprio(1);
#pragma unroll
        for (int ksl = 0; ksl < 4; ++ksl) {
            const int cb = ((ksl * 32) + hi * 16) ^ ((ql & 7) << 4);
            bf16x8 vf0 = *(const bf16x8*)(VtB + ql * 128 + cb);
            bf16x8 vf1 = *(const bf16x8*)(VtB + (32 + ql) * 128 + cb);
            const bf16x8 pv = (ksl == 0) ? pf0.v : (ksl == 1) ? pf1.v : (ksl == 2) ? pf2.v : pf3.v;
            accA = __builtin_amdgcn_mfma_f32_32x32x16_bf16(vf0, pv, accA, 0, 0, 0);
            accB = __builtin_amdgcn_mfma_f32_32x32x16_bf16(vf1, pv, accB, 0, 0, 0);
        }
        __builtin_amdgcn_s_setprio(0);

        if (more) {
            char* KsN = (char*)KsD[(kc & 1) ^ 1];
            char* VtN = (char*)VtD[(kc & 1) ^ 1];
            *(bf16x8*)(KsN + krow * 128 + kswz) = pk;
#pragma unroll
            for (int j = 0; j < 4; ++j) {
                u32 pkd = (u32)(unsigned short)pva[j] | ((u32)(unsigned short)pvb[j] << 16);
                const int d = dq * 4 + j;
                *(u32*)(VtN + d * 128 + ((4 * sp) ^ ((d & 7) << 4))) = pkd;
            }
            __syncthreads();
        }
    }

    const float il = 1.0f / l_run;
    short* orow = o_h + ((size_t)n * T_DIM + qrow) * HD;
#pragma unroll
    for (int rq = 0; rq < 4; ++rq) {
        uint2 st;
        st.x = cvtpk_bf16(accA[rq * 4 + 0] * il, accA[rq * 4 + 1] * il);
        st.y = cvtpk_bf16(accA[rq * 4 + 2] * il, accA[rq * 4 + 3] * il);
        *(uint2*)(orow + rq * 8 + hi * 4) = st;
        uint2 st2;
        st2.x = cvtpk_bf16(accB[rq * 4 + 0] * il, accB[rq * 4 + 1] * il);
        st2.y = cvtpk_bf16(accB[rq * 4 + 2] * il, accB[rq * 4 + 3] * il);
        *(uint2*)(orow + 32 + rq * 8 + hi * 4) = st2;
    }
    if (hi == 0) {
        m_arr[n * T_DIM + qrow] = m_run;
        l_arr[n * T_DIM + qrow] = l_run;
    }
}

// ---------------------------------------------------------------------------
// avg_weights: reg-prefetch dbuf + XCD swizzle (unchanged from round 5).
// ---------------------------------------------------------------------------
__global__ __launch_bounds__(256)
void colsum_mfma(const short* __restrict__ q_h, const short* __restrict__ k_h,
                 const float* __restrict__ m_arr, const float* __restrict__ l_arr,
                 float* __restrict__ avg_out)
{
    __shared__ short Qs[2][64][72];
    __shared__ float msh[2][64];
    __shared__ float lih[2][64];

    const int id = blockIdx.x;
    const int xcd = id & 7, slot = id >> 3;        // slot 0..263
    const int n = xcd * 8 + slot / 33;
    const int s0 = (slot % 33) * 64;

    const int tid = threadIdx.x, l = tid & 63, w = tid >> 6;
    const int lr = l & 15, lg = l >> 4;
    const int qr = tid >> 3, qcg = tid & 7;

    const short* qbase = q_h + (size_t)n * T_DIM * HD;

    bf16x8 ak[2];
#pragma unroll
    for (int c = 0; c < 2; ++c)
        ak[c] = *reinterpret_cast<const bf16x8*>(
            k_h + ((size_t)n * SPAD + s0 + w * 16 + lr) * HD + c * 32 + lg * 8);

    bf16x8 qa = *(const bf16x8*)(qbase + (size_t)qr * HD + qcg * 8);
    bf16x8 qb = *(const bf16x8*)(qbase + (size_t)(32 + qr) * HD + qcg * 8);
    float mlv = 0.f;
    if (tid < 64) mlv = m_arr[n * T_DIM + tid];
    else if (tid < 128) mlv = l_arr[n * T_DIM + tid - 64];
    *(bf16x8*)&Qs[0][qr][qcg * 8] = qa;
    *(bf16x8*)&Qs[0][32 + qr][qcg * 8] = qb;
    if (tid < 64) msh[0][tid] = mlv;
    else if (tid < 128) lih[0][tid - 64] = 1.0f / mlv;
    __syncthreads();

    float csum[4] = {0.f, 0.f, 0.f, 0.f};

    for (int it = 0; it < T_DIM / 64; ++it) {
        const int buf = it & 1;
        const bool more = (it + 1 < T_DIM / 64);
        if (more) {
            const int qo = (it + 1) * 64;
            qa = *(const bf16x8*)(qbase + (size_t)(qo + qr) * HD + qcg * 8);
            qb = *(const bf16x8*)(qbase + (size_t)(qo + 32 + qr) * HD + qcg * 8);
            if (tid < 64) mlv = m_arr[n * T_DIM + qo + tid];
            else if (tid < 128) mlv = l_arr[n * T_DIM + qo + tid - 64];
        }
        __builtin_amdgcn_s_setprio(1);
#pragma unroll
        for (int qt = 0; qt < 4; ++qt) {
            bf16x8 bq0 = *reinterpret_cast<const bf16x8*>(&Qs[buf][qt * 16 + lr][lg * 8]);
            bf16x8 bq1 = *reinterpret_cast<const bf16x8*>(&Qs[buf][qt * 16 + lr][32 + lg * 8]);
            f32x4 z = {0.f, 0.f, 0.f, 0.f};
            z = __builtin_amdgcn_mfma_f32_16x16x32_bf16(ak[0], bq0, z, 0, 0, 0);
            z = __builtin_amdgcn_mfma_f32_16x16x32_bf16(ak[1], bq1, z, 0, 0, 0);
            const float mq = msh[buf][qt * 16 + lr];
            const float lq = lih[buf][qt * 16 + lr];
#pragma unroll
            for (int r = 0; r < 4; ++r)
                csum[r] += exp2_fast(z[r] - mq) * lq;
        }
        __builtin_amdgcn_s_setprio(0);
        if (more) {
            *(bf16x8*)&Qs[buf ^ 1][qr][qcg * 8] = qa;
            *(bf16x8*)&Qs[buf ^ 1][32 + qr][qcg * 8] = qb;
            if (tid < 64) msh[buf ^ 1][tid] = mlv;
            else if (tid < 128) lih[buf ^ 1][tid - 64] = 1.0f / mlv;
            __syncthreads();
        }
    }

#pragma unroll
    for (int r = 0; r < 4; ++r) {
        float v = csum[r];
        v += __shfl_xor(v, 1, 16);
        v += __shfl_xor(v, 2, 16);
        v += __shfl_xor(v, 4, 16);
        v += __shfl_xor(v, 8, 16);
        if (lr == 0) {
            const int key = s0 + w * 16 + lg * 4 + r;
            if (key < SP1) avg_out[(size_t)n * SP1 + key] = v * 0.0625f;
        }
    }
}

// ---------------------------------------------------------------------------
extern "C" void kernel_launch(void* const* d_in, const int* in_sizes, int n_in,
                              void* d_out, int out_size, void* d_ws, size_t ws_size,
                              hipStream_t stream)
{
    const float* query   = (const float*)d_in[0];
    const float* key     = (const float*)d_in[1];
    const float* value   = (const float*)d_in[2];
    const float* wq      = (const float*)d_in[3];
    const float* wk      = (const float*)d_in[4];
    const float* wv      = (const float*)d_in[5];
    const float* in_bias = (const float*)d_in[6];
    const float* bias_k  = (const float*)d_in[7];
    const float* bias_v  = (const float*)d_in[8];
    const float* wo      = (const float*)d_in[9];
    const float* out_b   = (const float*)d_in[10];
    float* out = (float*)d_out;

    short* wqb = (short*)d_ws;                           // [4][1024][1024] bf16 (wq|wk|wv|wo)
    short* wob = wqb + (size_t)3 * E_DIM * E_DIM;
    short* q_h = wqb + (size_t)4 * E_DIM * E_DIM;        // [64][2048][64]
    short* k_h = q_h + (size_t)NH * T_DIM * HD;          // [64][2112][64]
    short* v_h = k_h + (size_t)NH * SPAD * HD;           // [64][2112][64]
    short* o_h = v_h + (size_t)NH * SPAD * HD;           // [64][2048][64]
    float* m_arr = (float*)(o_h + (size_t)NH * T_DIM * HD);
    float* l_arr = m_arr + (size_t)NH * T_DIM;

    const dim3 blk(256);
    hipLaunchKernelGGL(cvt_w4, dim3(512, 4), blk, 0, stream, wq, wk, wv, wo, wqb);

    hipLaunchKernelGGL((gemm_bf16<0>), dim3(64, 8, 3), blk, 0, stream,
                       (const void*)query, (const void*)key, (const void*)value,
                       wqb, in_bias, (void*)q_h);
    hipLaunchKernelGGL(fill_kv_pad, dim3(SPAD - S_DIM, NH), dim3(64), 0, stream,
                       k_h, v_h, bias_k, bias_v);
    hipLaunchKernelGGL(attn_mfma, dim3(512), dim3(512), 0, stream,
                       q_h, k_h, v_h, o_h, m_arr, l_arr);
    hipLaunchKernelGGL(colsum_mfma, dim3(2112), blk, 0, stream,
                       q_h, k_h, m_arr, l_arr, out + (size_t)T_DIM * B_DIM * E_DIM);
    hipLaunchKernelGGL((gemm_bf16<3>), dim3(64, 8), blk, 0, stream,
                       (const void*)o_h, (const void*)o_h, (const void*)o_h,
                       wob, out_b, (void*)out);
}

// Round 7
// 289.521 us; speedup vs baseline: 1.0694x; 1.0157x over previous
//
#include <hip/hip_runtime.h>

#define T_DIM 2048
#define B_DIM 4
#define S_DIM 2048
#define E_DIM 1024
#define H_NUM 16
#define HD    64
#define NH    64      // B*H
#define SP1   2049    // S+1 (bias token appended)
#define SPAD  2112    // 33*64, padded key length
#define NCHUNK 33
#define NTOKE ((size_t)T_DIM * B_DIM * E_DIM)   // 8192*1024

typedef short bf16x8 __attribute__((ext_vector_type(8)));
typedef short bf16x4 __attribute__((ext_vector_type(4)));
typedef float f32x4  __attribute__((ext_vector_type(4)));
typedef float f32x16 __attribute__((ext_vector_type(16)));
typedef unsigned int u32;

// log2(e): softmax done in exp2 domain; folded into Q projection scale.
#define QSCALE 0.18033688011112042f   // 0.125 * log2(e)

#if __has_builtin(__builtin_amdgcn_exp2f)
__device__ __forceinline__ float exp2_fast(float x) { return __builtin_amdgcn_exp2f(x); }
#else
__device__ __forceinline__ float exp2_fast(float x) { return __expf(x * 0.6931471805599453f); }
#endif

__device__ __forceinline__ unsigned short f2bf(float x) {
    union { float f; unsigned int u; } v; v.f = x;
    unsigned int r = v.u + 0x7FFFu + ((v.u >> 16) & 1u);   // RNE
    return (unsigned short)(r >> 16);
}

__device__ __forceinline__ u32 cvtpk_bf16(float lo, float hi) {
    u32 r;
    asm("v_cvt_pk_bf16_f32 %0, %1, %2" : "=v"(r) : "v"(lo), "v"(hi));
    return r;
}
__device__ __forceinline__ void plswap(u32& a, u32& b) {
    asm("v_permlane32_swap_b32 %0, %1" : "+v"(a), "+v"(b));
}

// async global->LDS, 16B per lane (m97 staging primitive)
__device__ __forceinline__ void load_lds16(const void* g, void* l) {
    __builtin_amdgcn_global_load_lds(
        (const __attribute__((address_space(1))) unsigned int*)g,
        (__attribute__((address_space(3))) unsigned int*)l, 16, 0, 0);
}

// ---------------------------------------------------------------------------
// weights f32 -> bf16 (wq|wk|wv|wo)
// ---------------------------------------------------------------------------
__global__ __launch_bounds__(256)
void cvt_w4(const float* __restrict__ w0, const float* __restrict__ w1,
            const float* __restrict__ w2, const float* __restrict__ w3,
            short* __restrict__ dst)
{
    const int y = blockIdx.y;
    const float* src = (y == 0) ? w0 : (y == 1) ? w1 : (y == 2) ? w2 : w3;
    short* d = dst + (size_t)y * E_DIM * E_DIM;
    const int i = blockIdx.x * 256 + threadIdx.x;     // 512*256 = E*E/8
    const float4* s = reinterpret_cast<const float4*>(src) + (size_t)i * 2;
    float4 a = s[0], b = s[1];
    uint4 o;
    o.x = cvtpk_bf16(a.x, a.y); o.y = cvtpk_bf16(a.z, a.w);
    o.z = cvtpk_bf16(b.x, b.y); o.w = cvtpk_bf16(b.z, b.w);
    *(reinterpret_cast<uint4*>(d) + i) = o;
}

// inputs q|k|v f32 -> bf16 contiguous [3][8192][1024]
__global__ __launch_bounds__(256)
void cvt_in(const float* __restrict__ q, const float* __restrict__ k,
            const float* __restrict__ v, short* __restrict__ dst)
{
    const int y = blockIdx.y;
    const float* src = (y == 0) ? q : (y == 1) ? k : v;
    short* d = dst + (size_t)y * NTOKE;
    const size_t i = (size_t)blockIdx.x * 256 + threadIdx.x;  // 4096*256 = NTOKE/8
    const float4* s = reinterpret_cast<const float4*>(src) + i * 2;
    float4 a = s[0], b = s[1];
    uint4 o;
    o.x = cvtpk_bf16(a.x, a.y); o.y = cvtpk_bf16(a.z, a.w);
    o.z = cvtpk_bf16(b.x, b.y); o.w = cvtpk_bf16(b.z, b.w);
    *(reinterpret_cast<uint4*>(d) + i) = o;
}

// ---------------------------------------------------------------------------
// m97-structure bf16 GEMM: 128x128 tile, BK=64, global_load_lds w16 into
// linear LDS, 2-barrier K-loop. MODE 0: QKV fused (z = blockIdx.z); MODE 3:
// out-proj (A gathered per-lane from head-major o_h; f32 output).
// ---------------------------------------------------------------------------
template<int MODE>
__global__ __launch_bounds__(256, 4)
void gemm_bf16(const short* __restrict__ Abase, const short* __restrict__ Wall,
               const float* __restrict__ biasAll, void* __restrict__ outp)
{
    __shared__ short As[128][64];
    __shared__ short Bs[128][64];
    const int bm = blockIdx.x, bn = blockIdx.y;
    const int z = (MODE == 0) ? blockIdx.z : 0;
    const short* Az = Abase + (MODE == 0 ? (size_t)z * NTOKE : 0);
    const short* W  = Wall + (size_t)z * E_DIM * E_DIM;
    const float* bias = biasAll + z * E_DIM;

    const int tid = threadIdx.x;
    const int l = tid & 63, w = tid >> 6;
    const int wr = w >> 1, wc = w & 1;
    const int lr = l & 15, lg = l >> 4;
    const int srow = tid >> 3, scol = (tid & 7) * 8;   // staging: 16B per lane

    f32x4 acc[4][4] = {};

    for (int k0 = 0; k0 < E_DIM; k0 += 64) {
        // ---- stage tile k0 (async, no VGPR round-trip) ----
#pragma unroll
        for (int r = 0; r < 4; ++r) {
            const int row = r * 32 + srow;
            const short* ga;
            if (MODE == 3) {
                const int m = bm * 128 + row;
                ga = Az + ((size_t)((m & 3) * 16 + (k0 >> 6)) * T_DIM + (m >> 2)) * HD + scol;
            } else {
                ga = Az + (size_t)(bm * 128 + row) * E_DIM + k0 + scol;
            }
            load_lds16(ga, &As[row][scol]);
            load_lds16(W + (size_t)(bn * 128 + row) * E_DIM + k0 + scol, &Bs[row][scol]);
        }
        __syncthreads();   // vmcnt(0) drain + barrier (compiler-enforced)

        __builtin_amdgcn_s_setprio(1);
#pragma unroll
        for (int c = 0; c < 2; ++c) {
            bf16x8 af[4], bf[4];
#pragma unroll
            for (int mi = 0; mi < 4; ++mi)
                af[mi] = *reinterpret_cast<const bf16x8*>(&As[wr * 64 + mi * 16 + lr][c * 32 + lg * 8]);
#pragma unroll
            for (int ni = 0; ni < 4; ++ni)
                bf[ni] = *reinterpret_cast<const bf16x8*>(&Bs[wc * 64 + ni * 16 + lr][c * 32 + lg * 8]);
#pragma unroll
            for (int mi = 0; mi < 4; ++mi)
#pragma unroll
                for (int ni = 0; ni < 4; ++ni)
                    acc[mi][ni] = __builtin_amdgcn_mfma_f32_16x16x32_bf16(
                        af[mi], bf[ni], acc[mi][ni], 0, 0, 0);
        }
        __builtin_amdgcn_s_setprio(0);
        __syncthreads();   // all reads done before next stage overwrites
    }

#pragma unroll
    for (int mi = 0; mi < 4; ++mi)
#pragma unroll
        for (int ni = 0; ni < 4; ++ni) {
            const int colg = bn * 128 + wc * 64 + ni * 16 + lr;
            const float bv = bias[colg];
#pragma unroll
            for (int r = 0; r < 4; ++r) {
                const int m = bm * 128 + wr * 64 + mi * 16 + lg * 4 + r;
                float v = acc[mi][ni][r] + bv;
                if (MODE == 3) {
                    ((float*)outp)[(size_t)m * E_DIM + colg] = v;
                } else {
                    if (z == 0) v *= QSCALE;
                    const int seq = m >> 2, b = m & 3;
                    const int head = colg >> 6, d = colg & 63;
                    const int sd = (z == 0) ? T_DIM : SPAD;
                    short* ob = (short*)outp;
                    if (z == 1) ob += (size_t)NH * T_DIM * HD;
                    else if (z == 2) ob += (size_t)NH * T_DIM * HD + (size_t)NH * SPAD * HD;
                    ob[((size_t)(b * 16 + head) * sd + seq) * HD + d] = (short)f2bf(v);
                }
            }
        }
}

// append bias_k/bias_v token at s=2048 (bf16), zero rows 2049..2111
__global__ void fill_kv_pad(short* __restrict__ k_h, short* __restrict__ v_h,
                            const float* __restrict__ bias_k,
                            const float* __restrict__ bias_v)
{
    const int d   = threadIdx.x;
    const int row = S_DIM + blockIdx.x;
    const int n   = blockIdx.y;
    short bk = 0, bv = 0;
    if (row == S_DIM) {
        bk = (short)f2bf(bias_k[(n & 15) * HD + d]);
        bv = (short)f2bf(bias_v[(n & 15) * HD + d]);
    }
    const size_t idx = ((size_t)n * SPAD + row) * HD + d;
    k_h[idx] = bk;
    v_h[idx] = bv;
}

// ---------------------------------------------------------------------------
// Swapped 32x32 MFMA flash attention, 8-wave blocks (256 q), grid 512.
// (unchanged from round 6)
// ---------------------------------------------------------------------------
__global__ __launch_bounds__(512, 4)
void attn_mfma(const short* __restrict__ q_h, const short* __restrict__ k_h,
               const short* __restrict__ v_h, short* __restrict__ o_h,
               float* __restrict__ m_arr, float* __restrict__ l_arr)
{
    __shared__ short KsD[2][64 * 64];
    __shared__ short VtD[2][64 * 64];

    const int id = blockIdx.x;
    const int xcd = id & 7, slot = id >> 3;        // slot 0..63
    const int n = xcd * 8 + (slot >> 3);
    const int q0 = (slot & 7) * 256;

    const int tid = threadIdx.x, l = tid & 63, w = tid >> 6;   // w 0..7
    const int ql = l & 31;
    const int hi = l >> 5;
    const int qrow = q0 + w * 32 + ql;

    const int krow = tid >> 3, kcg = tid & 7;
    const int kswz = (kcg * 16) ^ ((krow & 7) << 4);
    const int sp = tid & 31, dq = tid >> 5;

    const short* kbase = k_h + (size_t)n * SPAD * HD;
    const short* vbase = v_h + (size_t)n * SPAD * HD;

    bf16x8 aq0, aq1, aq2, aq3;
    {
        const short* qp = q_h + ((size_t)n * T_DIM + qrow) * HD + hi * 8;
        aq0 = *(const bf16x8*)(qp);
        aq1 = *(const bf16x8*)(qp + 16);
        aq2 = *(const bf16x8*)(qp + 32);
        aq3 = *(const bf16x8*)(qp + 48);
    }

    bf16x8 pk  = *(const bf16x8*)(kbase + (size_t)krow * HD + kcg * 8);
    bf16x4 pva = *(const bf16x4*)(vbase + (size_t)(2 * sp) * HD + dq * 4);
    bf16x4 pvb = *(const bf16x4*)(vbase + (size_t)(2 * sp + 1) * HD + dq * 4);
    {
        char* KsB = (char*)KsD[0];
        char* VtB = (char*)VtD[0];
        *(bf16x8*)(KsB + krow * 128 + kswz) = pk;
#pragma unroll
        for (int j = 0; j < 4; ++j) {
            u32 pkd = (u32)(unsigned short)pva[j] | ((u32)(unsigned short)pvb[j] << 16);
            const int d = dq * 4 + j;
            *(u32*)(VtB + d * 128 + ((4 * sp) ^ ((d & 7) << 4))) = pkd;
        }
    }
    __syncthreads();

    float m_run = -1e30f, l_run = 0.f;
    f32x16 accA, accB;
#pragma unroll
    for (int r = 0; r < 16; ++r) { accA[r] = 0.f; accB[r] = 0.f; }

    for (int kc = 0; kc < NCHUNK; ++kc) {
        const char* KsB = (const char*)KsD[kc & 1];
        const char* VtB = (const char*)VtD[kc & 1];
        const bool more = (kc + 1 < NCHUNK);

        if (more) {
            const int s0n = (kc + 1) * 64;
            pk  = *(const bf16x8*)(kbase + (size_t)(s0n + krow) * HD + kcg * 8);
            pva = *(const bf16x4*)(vbase + (size_t)(s0n + 2 * sp) * HD + dq * 4);
            pvb = *(const bf16x4*)(vbase + (size_t)(s0n + 2 * sp + 1) * HD + dq * 4);
        }

        f32x16 sc0, sc1;
#pragma unroll
        for (int r = 0; r < 16; ++r) { sc0[r] = 0.f; sc1[r] = 0.f; }
        __builtin_amdgcn_s_setprio(1);
#pragma unroll
        for (int sl = 0; sl < 4; ++sl) {
            const int cb = ((sl * 32) + hi * 16) ^ ((ql & 7) << 4);
            bf16x8 kf0 = *(const bf16x8*)(KsB + ql * 128 + cb);
            bf16x8 kf1 = *(const bf16x8*)(KsB + (32 + ql) * 128 + cb);
            bf16x8 qf = (sl == 0) ? aq0 : (sl == 1) ? aq1 : (sl == 2) ? aq2 : aq3;
            sc0 = __builtin_amdgcn_mfma_f32_32x32x16_bf16(kf0, qf, sc0, 0, 0, 0);
            sc1 = __builtin_amdgcn_mfma_f32_32x32x16_bf16(kf1, qf, sc1, 0, 0, 0);
        }
        __builtin_amdgcn_s_setprio(0);

        const int s0 = kc * 64;
        if (s0 + 64 > SP1) {
#pragma unroll
            for (int r = 0; r < 16; ++r) {
                const int key = (r & 3) + 8 * (r >> 2) + 4 * hi;
                if (s0 + key >= SP1)      sc0[r] = -1e30f;
                if (s0 + 32 + key >= SP1) sc1[r] = -1e30f;
            }
        }

        float mv[16];
#pragma unroll
        for (int r = 0; r < 16; ++r) mv[r] = fmaxf(sc0[r], sc1[r]);
#pragma unroll
        for (int s = 8; s > 0; s >>= 1)
#pragma unroll
            for (int r = 0; r < s; ++r) mv[r] = fmaxf(mv[r], mv[r + s]);
        float mx = fmaxf(mv[0], __shfl_xor(mv[0], 32));
        if (!__all(mx - m_run <= 8.0f)) {
            const float mnew = fmaxf(m_run, mx);
            const float fac = exp2_fast(m_run - mnew);
            l_run *= fac;
#pragma unroll
            for (int r = 0; r < 16; ++r) { accA[r] *= fac; accB[r] *= fac; }
            m_run = mnew;
        }
        float p0[16], p1[16];
#pragma unroll
        for (int r = 0; r < 16; ++r) p0[r] = exp2_fast(sc0[r] - m_run);
#pragma unroll
        for (int r = 0; r < 16; ++r) p1[r] = exp2_fast(sc1[r] - m_run);
        float sv[16];
#pragma unroll
        for (int r = 0; r < 16; ++r) sv[r] = p0[r] + p1[r];
#pragma unroll
        for (int s = 8; s > 0; s >>= 1)
#pragma unroll
            for (int r = 0; r < s; ++r) sv[r] += sv[r + s];
        l_run += sv[0] + __shfl_xor(sv[0], 32);

        union PF { u32 u[4]; bf16x8 v; };
        PF pf0, pf1, pf2, pf3;
        {
            u32 a0 = cvtpk_bf16(p0[0], p0[1]),   b0 = cvtpk_bf16(p0[4], p0[5]);   plswap(a0, b0);
            u32 a1 = cvtpk_bf16(p0[2], p0[3]),   b1 = cvtpk_bf16(p0[6], p0[7]);   plswap(a1, b1);
            u32 a2 = cvtpk_bf16(p0[8], p0[9]),   b2 = cvtpk_bf16(p0[12], p0[13]); plswap(a2, b2);
            u32 a3 = cvtpk_bf16(p0[10], p0[11]), b3 = cvtpk_bf16(p0[14], p0[15]); plswap(a3, b3);
            pf0.u[0] = a0; pf0.u[1] = a1; pf0.u[2] = b0; pf0.u[3] = b1;
            pf1.u[0] = a2; pf1.u[1] = a3; pf1.u[2] = b2; pf1.u[3] = b3;
            u32 c0 = cvtpk_bf16(p1[0], p1[1]),   d0_ = cvtpk_bf16(p1[4], p1[5]);   plswap(c0, d0_);
            u32 c1 = cvtpk_bf16(p1[2], p1[3]),   d1_ = cvtpk_bf16(p1[6], p1[7]);   plswap(c1, d1_);
            u32 c2 = cvtpk_bf16(p1[8], p1[9]),   d2_ = cvtpk_bf16(p1[12], p1[13]); plswap(c2, d2_);
            u32 c3 = cvtpk_bf16(p1[10], p1[11]), d3_ = cvtpk_bf16(p1[14], p1[15]); plswap(c3, d3_);
            pf2.u[0] = c0; pf2.u[1] = c1; pf2.u[2] = d0_; pf2.u[3] = d1_;
            pf3.u[0] = c2; pf3.u[1] = c3; pf3.u[2] = d2_; pf3.u[3] = d3_;
        }

        __builtin_amdgcn_s_setprio(1);
#pragma unroll
        for (int ksl = 0; ksl < 4; ++ksl) {
            const int cb = ((ksl * 32) + hi * 16) ^ ((ql & 7) << 4);
            bf16x8 vf0 = *(const bf16x8*)(VtB + ql * 128 + cb);
            bf16x8 vf1 = *(const bf16x8*)(VtB + (32 + ql) * 128 + cb);
            const bf16x8 pv = (ksl == 0) ? pf0.v : (ksl == 1) ? pf1.v : (ksl == 2) ? pf2.v : pf3.v;
            accA = __builtin_amdgcn_mfma_f32_32x32x16_bf16(vf0, pv, accA, 0, 0, 0);
            accB = __builtin_amdgcn_mfma_f32_32x32x16_bf16(vf1, pv, accB, 0, 0, 0);
        }
        __builtin_amdgcn_s_setprio(0);

        if (more) {
            char* KsN = (char*)KsD[(kc & 1) ^ 1];
            char* VtN = (char*)VtD[(kc & 1) ^ 1];
            *(bf16x8*)(KsN + krow * 128 + kswz) = pk;
#pragma unroll
            for (int j = 0; j < 4; ++j) {
                u32 pkd = (u32)(unsigned short)pva[j] | ((u32)(unsigned short)pvb[j] << 16);
                const int d = dq * 4 + j;
                *(u32*)(VtN + d * 128 + ((4 * sp) ^ ((d & 7) << 4))) = pkd;
            }
            __syncthreads();
        }
    }

    const float il = 1.0f / l_run;
    short* orow = o_h + ((size_t)n * T_DIM + qrow) * HD;
#pragma unroll
    for (int rq = 0; rq < 4; ++rq) {
        uint2 st;
        st.x = cvtpk_bf16(accA[rq * 4 + 0] * il, accA[rq * 4 + 1] * il);
        st.y = cvtpk_bf16(accA[rq * 4 + 2] * il, accA[rq * 4 + 3] * il);
        *(uint2*)(orow + rq * 8 + hi * 4) = st;
        uint2 st2;
        st2.x = cvtpk_bf16(accB[rq * 4 + 0] * il, accB[rq * 4 + 1] * il);
        st2.y = cvtpk_bf16(accB[rq * 4 + 2] * il, accB[rq * 4 + 3] * il);
        *(uint2*)(orow + 32 + rq * 8 + hi * 4) = st2;
    }
    if (hi == 0) {
        m_arr[n * T_DIM + qrow] = m_run;
        l_arr[n * T_DIM + qrow] = l_run;
    }
}

// ---------------------------------------------------------------------------
// avg_weights (unchanged from round 6)
// ---------------------------------------------------------------------------
__global__ __launch_bounds__(256)
void colsum_mfma(const short* __restrict__ q_h, const short* __restrict__ k_h,
                 const float* __restrict__ m_arr, const float* __restrict__ l_arr,
                 float* __restrict__ avg_out)
{
    __shared__ short Qs[2][64][72];
    __shared__ float msh[2][64];
    __shared__ float lih[2][64];

    const int id = blockIdx.x;
    const int xcd = id & 7, slot = id >> 3;        // slot 0..263
    const int n = xcd * 8 + slot / 33;
    const int s0 = (slot % 33) * 64;

    const int tid = threadIdx.x, l = tid & 63, w = tid >> 6;
    const int lr = l & 15, lg = l >> 4;
    const int qr = tid >> 3, qcg = tid & 7;

    const short* qbase = q_h + (size_t)n * T_DIM * HD;

    bf16x8 ak[2];
#pragma unroll
    for (int c = 0; c < 2; ++c)
        ak[c] = *reinterpret_cast<const bf16x8*>(
            k_h + ((size_t)n * SPAD + s0 + w * 16 + lr) * HD + c * 32 + lg * 8);

    bf16x8 qa = *(const bf16x8*)(qbase + (size_t)qr * HD + qcg * 8);
    bf16x8 qb = *(const bf16x8*)(qbase + (size_t)(32 + qr) * HD + qcg * 8);
    float mlv = 0.f;
    if (tid < 64) mlv = m_arr[n * T_DIM + tid];
    else if (tid < 128) mlv = l_arr[n * T_DIM + tid - 64];
    *(bf16x8*)&Qs[0][qr][qcg * 8] = qa;
    *(bf16x8*)&Qs[0][32 + qr][qcg * 8] = qb;
    if (tid < 64) msh[0][tid] = mlv;
    else if (tid < 128) lih[0][tid - 64] = 1.0f / mlv;
    __syncthreads();

    float csum[4] = {0.f, 0.f, 0.f, 0.f};

    for (int it = 0; it < T_DIM / 64; ++it) {
        const int buf = it & 1;
        const bool more = (it + 1 < T_DIM / 64);
        if (more) {
            const int qo = (it + 1) * 64;
            qa = *(const bf16x8*)(qbase + (size_t)(qo + qr) * HD + qcg * 8);
            qb = *(const bf16x8*)(qbase + (size_t)(qo + 32 + qr) * HD + qcg * 8);
            if (tid < 64) mlv = m_arr[n * T_DIM + qo + tid];
            else if (tid < 128) mlv = l_arr[n * T_DIM + qo + tid - 64];
        }
        __builtin_amdgcn_s_setprio(1);
#pragma unroll
        for (int qt = 0; qt < 4; ++qt) {
            bf16x8 bq0 = *reinterpret_cast<const bf16x8*>(&Qs[buf][qt * 16 + lr][lg * 8]);
            bf16x8 bq1 = *reinterpret_cast<const bf16x8*>(&Qs[buf][qt * 16 + lr][32 + lg * 8]);
            f32x4 z = {0.f, 0.f, 0.f, 0.f};
            z = __builtin_amdgcn_mfma_f32_16x16x32_bf16(ak[0], bq0, z, 0, 0, 0);
            z = __builtin_amdgcn_mfma_f32_16x16x32_bf16(ak[1], bq1, z, 0, 0, 0);
            const float mq = msh[buf][qt * 16 + lr];
            const float lq = lih[buf][qt * 16 + lr];
#pragma unroll
            for (int r = 0; r < 4; ++r)
                csum[r] += exp2_fast(z[r] - mq) * lq;
        }
        __builtin_amdgcn_s_setprio(0);
        if (more) {
            *(bf16x8*)&Qs[buf ^ 1][qr][qcg * 8] = qa;
            *(bf16x8*)&Qs[buf ^ 1][32 + qr][qcg * 8] = qb;
            if (tid < 64) msh[buf ^ 1][tid] = mlv;
            else if (tid < 128) lih[buf ^ 1][tid - 64] = 1.0f / mlv;
            __syncthreads();
        }
    }

#pragma unroll
    for (int r = 0; r < 4; ++r) {
        float v = csum[r];
        v += __shfl_xor(v, 1, 16);
        v += __shfl_xor(v, 2, 16);
        v += __shfl_xor(v, 4, 16);
        v += __shfl_xor(v, 8, 16);
        if (lr == 0) {
            const int key = s0 + w * 16 + lg * 4 + r;
            if (key < SP1) avg_out[(size_t)n * SP1 + key] = v * 0.0625f;
        }
    }
}

// ---------------------------------------------------------------------------
extern "C" void kernel_launch(void* const* d_in, const int* in_sizes, int n_in,
                              void* d_out, int out_size, void* d_ws, size_t ws_size,
                              hipStream_t stream)
{
    const float* query   = (const float*)d_in[0];
    const float* key     = (const float*)d_in[1];
    const float* value   = (const float*)d_in[2];
    const float* wq      = (const float*)d_in[3];
    const float* wk      = (const float*)d_in[4];
    const float* wv      = (const float*)d_in[5];
    const float* in_bias = (const float*)d_in[6];
    const float* bias_k  = (const float*)d_in[7];
    const float* bias_v  = (const float*)d_in[8];
    const float* wo      = (const float*)d_in[9];
    const float* out_b   = (const float*)d_in[10];
    float* out = (float*)d_out;

    short* wqb    = (short*)d_ws;                        // [4][1024][1024] bf16
    short* wob    = wqb + (size_t)3 * E_DIM * E_DIM;
    short* qkv_bf = wqb + (size_t)4 * E_DIM * E_DIM;     // [3][8192][1024] bf16
    short* q_h = qkv_bf + 3 * NTOKE;                     // [64][2048][64]
    short* k_h = q_h + (size_t)NH * T_DIM * HD;          // [64][2112][64]
    short* v_h = k_h + (size_t)NH * SPAD * HD;           // [64][2112][64]
    short* o_h = v_h + (size_t)NH * SPAD * HD;           // [64][2048][64]
    float* m_arr = (float*)(o_h + (size_t)NH * T_DIM * HD);
    float* l_arr = m_arr + (size_t)NH * T_DIM;

    const dim3 blk(256);
    hipLaunchKernelGGL(cvt_w4, dim3(512, 4), blk, 0, stream, wq, wk, wv, wo, wqb);
    hipLaunchKernelGGL(cvt_in, dim3(4096, 3), blk, 0, stream, query, key, value, qkv_bf);

    hipLaunchKernelGGL((gemm_bf16<0>), dim3(64, 8, 3), blk, 0, stream,
                       qkv_bf, wqb, in_bias, (void*)q_h);
    hipLaunchKernelGGL(fill_kv_pad, dim3(SPAD - S_DIM, NH), dim3(64), 0, stream,
                       k_h, v_h, bias_k, bias_v);
    hipLaunchKernelGGL(attn_mfma, dim3(512), dim3(512), 0, stream,
                       q_h, k_h, v_h, o_h, m_arr, l_arr);
    hipLaunchKernelGGL(colsum_mfma, dim3(2112), blk, 0, stream,
                       q_h, k_h, m_arr, l_arr, out + (size_t)T_DIM * B_DIM * E_DIM);
    hipLaunchKernelGGL((gemm_bf16<3>), dim3(64, 8), blk, 0, stream,
                       o_h, wob, out_b, (void*)out);
}